// Round 1
// baseline (800.743 us; speedup 1.0000x reference)
//
#include <hip/hip_runtime.h>
#include <stdint.h>

#define B_ROWS 1024
#define DDIM   2048
#define NFEAT  30000

#define BM 128
#define BN 128
#define BK 64

typedef __attribute__((ext_vector_type(8))) short short8;
typedef __attribute__((ext_vector_type(4))) float v4f;

typedef const __attribute__((address_space(1))) unsigned int* gptr_t;
typedef __attribute__((address_space(3))) unsigned int* lptr_t;

__device__ __forceinline__ unsigned short f32_to_bf16(float f) {
    unsigned int u = __float_as_uint(f);
    // round-to-nearest-even (inputs are finite gaussians; no NaN handling needed)
    unsigned int r = u + 0x7FFFu + ((u >> 16) & 1u);
    return (unsigned short)(r >> 16);
}

__device__ __forceinline__ void async_copy16(const unsigned short* g, unsigned short* l) {
    // global -> LDS direct copy, 16 B per lane; LDS dest = wave-uniform base + lane*16
    __builtin_amdgcn_global_load_lds((gptr_t)g, (lptr_t)l, 16, 0, 0);
}

// ---------------- convert f32 -> bf16 (vectorized, grid-stride) ----------------
__global__ void f32_to_bf16_kernel(const float4* __restrict__ src,
                                   ushort4* __restrict__ dst, int n4) {
    int stride = gridDim.x * blockDim.x;
    for (int i = blockIdx.x * blockDim.x + threadIdx.x; i < n4; i += stride) {
        float4 v = src[i];
        ushort4 o;
        o.x = f32_to_bf16(v.x);
        o.y = f32_to_bf16(v.y);
        o.z = f32_to_bf16(v.z);
        o.w = f32_to_bf16(v.w);
        dst[i] = o;
    }
}

// ---------------- f32 copy (vectorized, grid-stride) ----------------
__global__ void copy_f32_kernel(const float4* __restrict__ src,
                                float4* __restrict__ dst, int n4) {
    int stride = gridDim.x * blockDim.x;
    for (int i = blockIdx.x * blockDim.x + threadIdx.x; i < n4; i += stride) {
        dst[i] = src[i];
    }
}

// ---------------- bf16 NT-GEMM: C[B_ROWS][NFEAT] = A[B_ROWS][D] * Bf[NFEAT][D]^T ----------------
// m97-style: 128x128 tile, BK=64, 256 threads (4 waves, 2x2), 4x4 16x16x32 MFMAs/wave,
// global_load_lds width-16 staging.
__global__ __launch_bounds__(256) void gemm_bf16_kernel(
    const unsigned short* __restrict__ A,   // [1024][2048] bf16
    const unsigned short* __restrict__ Bf,  // [30000][2048] bf16
    float* __restrict__ C)                  // [1024][30000] f32
{
    __shared__ unsigned short As[BM * BK];  // 16 KB
    __shared__ unsigned short Bs[BN * BK];  // 16 KB

    const int bid  = blockIdx.x;
    const int mblk = bid & 7;    // m fastest -> concurrent blocks share features stripe (LLC reuse)
    const int nblk = bid >> 3;
    const int tid  = threadIdx.x;
    const int wave = tid >> 6;
    const int lane = tid & 63;
    const int wm = wave & 1;     // 2x2 wave grid, each wave does 64x64
    const int wn = wave >> 1;

    // staging addressing: chunk = wave*4+i covers tile rows [chunk*8, chunk*8+8)
    // lane l -> row chunk*8 + l/8, col elems (l%8)*8  (matches HW lane*16B LDS scatter)
    const int ldrow = lane >> 3;
    const int ldcol = (lane & 7) * 8;

    const unsigned short* a_src[4];
    const unsigned short* b_src[4];
    unsigned short* a_dst[4];
    unsigned short* b_dst[4];
#pragma unroll
    for (int i = 0; i < 4; ++i) {
        int chunk = wave * 4 + i;
        int ar = mblk * BM + chunk * 8 + ldrow;
        int br = nblk * BN + chunk * 8 + ldrow;
        if (br >= NFEAT) br = NFEAT - 1;           // clamp tail rows (stores are guarded)
        a_src[i] = A  + (size_t)ar * DDIM + ldcol;
        b_src[i] = Bf + (size_t)br * DDIM + ldcol;
        a_dst[i] = &As[chunk * 512];               // wave-uniform LDS base (1 KB per inst)
        b_dst[i] = &Bs[chunk * 512];
    }

    v4f acc[4][4];
#pragma unroll
    for (int im = 0; im < 4; ++im)
#pragma unroll
        for (int in = 0; in < 4; ++in)
            acc[im][in] = (v4f){0.f, 0.f, 0.f, 0.f};

    for (int kt = 0; kt < DDIM / BK; ++kt) {
        __syncthreads();   // previous compute done before LDS overwrite
#pragma unroll
        for (int i = 0; i < 4; ++i) {
            async_copy16(a_src[i] + kt * BK, a_dst[i]);
            async_copy16(b_src[i] + kt * BK, b_dst[i]);
        }
        __syncthreads();   // compiler drains vmcnt before s_barrier

#pragma unroll
        for (int kk = 0; kk < BK; kk += 32) {
            const int koff = kk + (lane >> 4) * 8;
            short8 afrag[4], bfrag[4];
#pragma unroll
            for (int im = 0; im < 4; ++im)
                afrag[im] = *(const short8*)&As[(wm * 64 + im * 16 + (lane & 15)) * BK + koff];
#pragma unroll
            for (int in = 0; in < 4; ++in)
                bfrag[in] = *(const short8*)&Bs[(wn * 64 + in * 16 + (lane & 15)) * BK + koff];
#pragma unroll
            for (int im = 0; im < 4; ++im)
#pragma unroll
                for (int in = 0; in < 4; ++in)
                    acc[im][in] = __builtin_amdgcn_mfma_f32_16x16x32_bf16(
                        afrag[im], bfrag[in], acc[im][in], 0, 0, 0);
        }
    }

    // epilogue: C/D layout col = lane&15, row = (lane>>4)*4 + reg
    const int m_base = mblk * BM + wm * 64;
    const int n_base = nblk * BN + wn * 64;
#pragma unroll
    for (int im = 0; im < 4; ++im) {
        int m0 = m_base + im * 16 + (lane >> 4) * 4;
#pragma unroll
        for (int in = 0; in < 4; ++in) {
            int n = n_base + in * 16 + (lane & 15);
            if (n < NFEAT) {
#pragma unroll
                for (int r = 0; r < 4; ++r)
                    C[(size_t)(m0 + r) * NFEAT + n] = acc[im][in][r];
            }
        }
    }
}

// ---------------- scatter: last-writer-wins row overwrite ----------------
__global__ void scatter_rows_kernel(const float* __restrict__ inputs,
                                    const int* __restrict__ idx,
                                    const int* __restrict__ uf,
                                    float* __restrict__ out_feats) {
    int b = blockIdx.x;
    if (uf[b] <= 0) return;
    int y = idx[b];
    __shared__ int dead;
    if (threadIdx.x == 0) dead = 0;
    __syncthreads();
    for (int b2 = b + 1 + threadIdx.x; b2 < B_ROWS; b2 += blockDim.x) {
        if (uf[b2] > 0 && idx[b2] == y) { dead = 1; break; }
    }
    __syncthreads();
    if (dead) return;
    // winner: overwrite row y with inputs[b] (already unit-norm; renorm is a ~1e-7 no-op)
    const float4* s = (const float4*)(inputs + (size_t)b * DDIM);
    float4* d = (float4*)(out_feats + (size_t)y * DDIM);
    for (int i = threadIdx.x; i < DDIM / 4; i += blockDim.x) d[i] = s[i];
}

extern "C" void kernel_launch(void* const* d_in, const int* in_sizes, int n_in,
                              void* d_out, int out_size, void* d_ws, size_t ws_size,
                              hipStream_t stream) {
    const float* inputs   = (const float*)d_in[0];   // [1024][2048]
    const float* features = (const float*)d_in[1];   // [30000][2048]
    // d_in[2] = IoU (unused by max_iou path)
    const int* indexes    = (const int*)d_in[3];     // [1024]
    const int* uf         = (const int*)d_in[4];     // [1024]

    float* out0 = (float*)d_out;                         // [1024][30000]
    float* out1 = out0 + (size_t)B_ROWS * NFEAT;         // [30000][2048]

    // bf16 scratch lives inside the out1 slot (126.9 MB used of 245.8 MB);
    // it is overwritten by the f32 copy AFTER the GEMM (stream-ordered).
    unsigned short* featB = (unsigned short*)out1;
    unsigned short* inpB  = featB + (size_t)NFEAT * DDIM;

    const int nf4 = NFEAT * DDIM / 4;    // 15,360,000
    const int na4 = B_ROWS * DDIM / 4;   // 524,288

    f32_to_bf16_kernel<<<8192, 256, 0, stream>>>((const float4*)features, (ushort4*)featB, nf4);
    f32_to_bf16_kernel<<<2048, 256, 0, stream>>>((const float4*)inputs, (ushort4*)inpB, na4);

    const int n_nblk = (NFEAT + BN - 1) / BN;  // 235
    gemm_bf16_kernel<<<8 * n_nblk, 256, 0, stream>>>(inpB, featB, out0);

    copy_f32_kernel<<<8192, 256, 0, stream>>>((const float4*)features, (float4*)out1, nf4);
    scatter_rows_kernel<<<B_ROWS, 256, 0, stream>>>(inputs, indexes, uf, out1);
}